// Round 6
// baseline (330.871 us; speedup 1.0000x reference)
//
#include <hip/hip_runtime.h>

// Problem constants
#define BATCH 4096
#define CCH   22
#define TT    1001   // usable time samples (row length 1002; last elem = subject id)
#define TROW  1002
#define KOUT  40
#define KSZ   25
#define WOUT  977    // 1001 - 25 + 1
#define POOLW 100
#define NWIN  9
#define FEAT  360
#define NOUT  4

// Conv-MFMA tiling: 2 blocks along w, 512 computed w each, exclusive ownership
//   block 0: computes [0,512),   owns [0,500)    -> pool wins 0..4  (win0=0)
//   block 1: computes [488,1000) owns [500,977)  -> pool wins 5..8 + pseudo (win0=4)
// Every pool window has exactly ONE owning block (split at w=500, a POOLW edge).
#define WBLK  512
#define NWB   2
#define NBLK  (BATCH * NWB)    // 8192
//
// im2col-by-stride: LDS x-tile is [t][c] bf16 with row stride EXACTLY CSTG=24
// elements (48 B). Flattened reduction index f = j*24 + c is LINEAR in LDS
// (byte = w*48 + 2*f), so MFMA A-fragments are contiguous b128 reads crossing
// tap boundaries. K-steps: ceil(25*24/32) = 19. Pads (c in {22,23}, f >= 600)
// are neutralized by zeroed WEIGHTS; A may read arbitrary finite staged data.
#define CSTG  24               // padded channels (row = 48 B, 16B-aligned b128)
#define ROWB  48               // LDS row stride bytes
#define TSTG  544              // rows staged (need 537 = 512 + 25); 17 groups of 32
#define FKK   19               // MFMA K-steps of 32 over flattened (j,c)
#define KP    48               // k_out padded to 3 MFMA n-tiles
#define NLOC  7                // pool-window slots per block (wins win0..win0+6)
#define NMT   8                // m-tiles per wave (wave covers 128 w)

typedef __attribute__((ext_vector_type(8))) short short8;
typedef __attribute__((ext_vector_type(4))) float floatx4;

__device__ __forceinline__ unsigned short f2bf(float f) {
    unsigned u = __float_as_uint(f);
    u += 0x7fff + ((u >> 16) & 1);          // round-to-nearest-even
    return (unsigned short)(u >> 16);
}
// HW packed f32->bf16 RNE convert (same rounding as f2bf, 1 instr for 2 vals)
__device__ __forceinline__ unsigned cvt_pk_bf16(float a, float b) {
    unsigned r;
    asm("v_cvt_pk_bf16_f32 %0, %1, %2" : "=v"(r) : "v"(a), "v"(b));
    return r;
}
__device__ __forceinline__ float eluf(float v) {
    return v > 0.0f ? v : __expf(v) - 1.0f;
}

// Pack conv weights into MFMA B-operand layout over the flattened reduction:
// wp[kk][n=0..47][e=0..31] bf16, where f = kk*32+e, j = f/24, c = f%24.
__global__ __launch_bounds__(256) void pack_w_kernel(const float* __restrict__ cw,
                                                     unsigned short* __restrict__ wp) {
    int i = blockIdx.x * 256 + threadIdx.x;      // over FKK*KP*32 = 29184
    if (i >= FKK * KP * 32) return;
    int e = i & 31;
    int n = (i >> 5) % KP;
    int kk = i / (KP * 32);
    int f = kk * 32 + e;
    int j = f / CSTG, c = f - j * CSTG;
    float v = (n < KOUT && c < CCH && j < KSZ) ? cw[(n * CCH + c) * KSZ + j] : 0.0f;
    wp[i] = f2bf(v);
}

// Conv(bf16 MFMA) + bias + ELU + owned pool-window sums + owned BN partials.
// grid (NWB, BATCH), block 256 = 4 waves; wave wv owns 128 w's (8 m-tiles).
// kk-loop: A-side is an enforced in-flight pipeline — asm-volatile
// ds_read_b128 ping-pong with COUNTED s_waitcnt lgkmcnt(8): the 8 reads for
// train kk+1 stay outstanding DURING train kk (DS pipe busy under the MFMA
// train), and sched_barrier(0) after each wait stops MFMA hoisting (rule #18).
// B-side stays plain C++ (3 L1-resident loads, compiler-managed vmcnt).
__global__ __launch_bounds__(256, 2) void conv_mfma_kernel(
        const float* __restrict__ x, const unsigned short* __restrict__ wp,
        const float* __restrict__ cb, float* __restrict__ pparts,
        float* __restrict__ spS, float* __restrict__ spQ) {
    __shared__ __align__(16) unsigned short xt[TSTG * CSTG];  // 544*48 B = 26112 B
    __shared__ float ps_s[NLOC * KP];                  // 1344 B
    __shared__ float st_q[KP];                         // 192 B

    const int bx = blockIdx.x, b = blockIdx.y;
    const int w0     = bx ? 488 : 0;     // first computed w
    const int ostart = bx ? 500 : 0;     // ownership [ostart, oend)
    const int oend   = bx ? WOUT : 500;
    const int win0   = bx ? 4 : 0;       // slot s holds pool window win0+s
    const int tid = threadIdx.x;
    const int wv = __builtin_amdgcn_readfirstlane(tid >> 6);
    const int lane = tid & 63;
    const size_t xb = (size_t)b * (CCH * TROW);

    for (int i = tid; i < NLOC * KP + KP; i += 256) {
        if (i < NLOC * KP) ps_s[i] = 0.0f;
        else st_q[i - NLOC * KP] = 0.0f;
    }

    // ---- stage x -> xt[t][c] bf16, row stride 48 B ----
    // 17 groups of 32 rows; lane = (row-in-group r5, c-half h of 12 channels)
    {
        const int r5 = lane & 31, h = lane >> 5;
#pragma unroll
        for (int it = 0; it < 5; ++it) {
            int idx = it * 4 + wv;                   // 0..19, active 0..16
            if (idx < 17) {
                int t_loc = idx * 32 + r5;
                int t_gl = w0 + t_loc;
                float v[12];
#pragma unroll
                for (int r = 0; r < 12; ++r) {
                    int c = h * 12 + r;
                    v[r] = (c < CCH && t_gl < TT) ? x[xb + (size_t)c * TROW + t_gl] : 0.0f;
                }
                unsigned u[6];
#pragma unroll
                for (int r = 0; r < 6; ++r) u[r] = cvt_pk_bf16(v[2 * r], v[2 * r + 1]);
                char* dst = (char*)xt + t_loc * ROWB + h * 24;
                *(uint2*)(dst)      = make_uint2(u[0], u[1]);
                *(uint2*)(dst + 8)  = make_uint2(u[2], u[3]);
                *(uint2*)(dst + 16) = make_uint2(u[4], u[5]);
            }
        }
    }
    __syncthreads();

    // ---- MFMA kk-loop: 19 K-steps of 32 over flattened (j,c), acc preloaded w/ bias ----
    const int m16 = lane & 15, g = lane >> 4;
    floatx4 acc[NMT][3];
#pragma unroll
    for (int nt = 0; nt < 3; ++nt) {
        int k = nt * 16 + m16;
        float bv = (k < KOUT) ? cb[k] : 0.0f;
#pragma unroll
        for (int mt = 0; mt < NMT; ++mt) acc[mt][nt] = (floatx4){bv, bv, bv, bv};
    }

    // LDS byte address for asm ds_read (addrspace(3) pointer cast -> DS offset)
    unsigned aaddr = (unsigned)(size_t)(void*)xt
                   + (unsigned)((wv * 128 + m16) * ROWB + g * 16);
    const unsigned short* wq = wp + m16 * 32 + g * 8;

    short8 aA[8], aB[8], bA[3], bB[3];

#define DSR(d, o) asm volatile("ds_read_b128 %0, %1 offset:" #o                \
                               : "=v"(d) : "v"(aaddr))
#define RD8(A, o0,o1,o2,o3,o4,o5,o6,o7)                                        \
    DSR(A[0],o0); DSR(A[1],o1); DSR(A[2],o2); DSR(A[3],o3);                    \
    DSR(A[4],o4); DSR(A[5],o5); DSR(A[6],o6); DSR(A[7],o7)
#define WAITL(n) do { asm volatile("s_waitcnt lgkmcnt(" #n ")" ::: "memory");  \
                      __builtin_amdgcn_sched_barrier(0); } while (0)
#define TRAIN(af, bf)                                                          \
    _Pragma("unroll")                                                          \
    for (int q = 0; q < NMT; ++q)                                              \
        _Pragma("unroll")                                                      \
        for (int nt = 0; nt < 3; ++nt)                                         \
            acc[q][nt] = __builtin_amdgcn_mfma_f32_16x16x32_bf16(              \
                af[q], bf[nt], acc[q][nt], 0, 0, 0);

    // prologue: A-frags kk=0 in flight (8 outstanding); B kk=0 via C++
    RD8(aA, 0,768,1536,2304,3072,3840,4608,5376);
#pragma unroll
    for (int nt = 0; nt < 3; ++nt) bA[nt] = *(const short8*)(wq + nt * 16 * 32);

#pragma unroll 1
    for (int it2 = 0; it2 < 9; ++it2) {          // trains kk = 2*it2, 2*it2+1
        RD8(aB, 64,832,1600,2368,3136,3904,4672,5440);   // A kk+1 (out: 16)
#pragma unroll
        for (int nt = 0; nt < 3; ++nt)                    // B kk+1
            bB[nt] = *(const short8*)(wq + (KP * 32) + nt * 16 * 32);
        WAITL(8);                                         // aA landed; aB in flight
        TRAIN(aA, bA);                                    // train kk
        RD8(aA, 128,896,1664,2432,3200,3968,4736,5504);  // A kk+2 (out: 16)
#pragma unroll
        for (int nt = 0; nt < 3; ++nt)                    // B kk+2 (kk+2 <= 18 always)
            bA[nt] = *(const short8*)(wq + 2 * (KP * 32) + nt * 16 * 32);
        WAITL(8);                                         // aB landed; aA in flight
        TRAIN(aB, bB);                                    // train kk+1
        aaddr += 128;
        wq += 2 * (KP * 32);
    }
    WAITL(0);                                             // last aA landed
    TRAIN(aA, bA);                                        // tail train kk = 18

#undef DSR
#undef RD8
#undef WAITL
#undef TRAIN

    // ---- epilogue: ELU, ownership mask, pool segmented-reduce, BN sumsq ----
    float qv[3] = {0.f, 0.f, 0.f};
#pragma unroll
    for (int mt = 0; mt < NMT; ++mt) {
        const int wbase = w0 + wv * 128 + mt * 16 + g * 4;  // 4-aligned quad
        const int win = wbase / POOLW;                      // quad never straddles
#pragma unroll
        for (int nt = 0; nt < 3; ++nt) {
            const int k = nt * 16 + m16;
            const bool kok = (k < KOUT);
            float psum = 0.f;
#pragma unroll
            for (int r = 0; r < 4; ++r) {
                int w = wbase + r;
                float e = eluf(acc[mt][nt][r]);
                e = (kok && w >= ostart && w < oend) ? e : 0.0f;  // exclusive ownership
                psum += e;
                qv[nt] = fmaf(e, e, qv[nt]);
            }
            // segmented reduce over the 4 row-groups (g), segments g-contiguous
            float o1 = __shfl_down(psum, 16); int w1 = __shfl_down(win, 16);
            if (lane < 48 && w1 == win) psum += o1;
            float o2 = __shfl_down(psum, 32); int w2 = __shfl_down(win, 32);
            if (lane < 32 && w2 == win) psum += o2;
            int wu = __shfl_up(win, 16);
            if (g == 0 || wu != win)
                atomicAdd(&ps_s[(win - win0) * KP + k], psum);
        }
    }
#pragma unroll
    for (int nt = 0; nt < 3; ++nt) {
        float q = qv[nt];
        q += __shfl_xor(q, 16);
        q += __shfl_xor(q, 32);
        if (g == 0) atomicAdd(&st_q[nt * 16 + m16], q);
    }
    __syncthreads();

    const int blk = b * NWB + bx;
    if (tid < KOUT) {
        // stats sum = sum of all owned pool slots (incl. pseudo/zero windows)
        float s = 0.0f;
#pragma unroll
        for (int wl = 0; wl < NLOC; ++wl) s += ps_s[wl * KP + tid];
        spS[(size_t)tid * NBLK + blk] = s;               // transposed: coalesced reduce
        spQ[(size_t)tid * NBLK + blk] = st_q[tid];
    }
    for (int i = tid; i < NLOC * KOUT; i += 256) {
        int wl = i / KOUT, k = i - wl * KOUT;
        pparts[((size_t)blk * NLOC + wl) * KOUT + k] = ps_s[wl * KP + k];
    }
}

// Reduce per-block stat partials -> BN scale/shift per k. grid KOUT.
__global__ __launch_bounds__(256) void bn_stats_kernel(
        const float* __restrict__ spS, const float* __restrict__ spQ,
        const float* __restrict__ gamma, const float* __restrict__ beta,
        float* __restrict__ scale, float* __restrict__ shift) {
    const int k = blockIdx.x;
    float s = 0.0f, q = 0.0f;
    for (int r = threadIdx.x; r < NBLK; r += 256) {
        s += spS[(size_t)k * NBLK + r];
        q += spQ[(size_t)k * NBLK + r];
    }
#pragma unroll
    for (int m = 32; m; m >>= 1) {
        s += __shfl_xor(s, m, 64);
        q += __shfl_xor(q, m, 64);
    }
    __shared__ float rs[4], rq[4];
    const int wid = threadIdx.x >> 6, lane = threadIdx.x & 63;
    if (lane == 0) { rs[wid] = s; rq[wid] = q; }
    __syncthreads();
    if (threadIdx.x == 0) {
        s = rs[0] + rs[1] + rs[2] + rs[3];
        q = rq[0] + rq[1] + rq[2] + rq[3];
        const float N = (float)BATCH * (float)WOUT;
        float mean = s / N;
        float var = q / N - mean * mean;
        float sc = gamma[k] / sqrtf(var + 1e-5f);
        scale[k] = sc;
        shift[k] = beta[k] - mean * sc;
    }
}

// Subject decode + BN-affine fold + 360x4 matvec.
// Each pool window has exactly one source slot:
//   win 0..4 -> block 0 slot win        (unit index win)
//   win 5..8 -> block 1 slot win-4      (unit index NLOC + win-4 = win+3)
__global__ __launch_bounds__(64) void fc_kernel(
        const float* __restrict__ x, const float* __restrict__ pparts,
        const float* __restrict__ scale, const float* __restrict__ shift,
        const float* __restrict__ fcw, const float* __restrict__ fcb,
        float* __restrict__ out) {
    const int b = blockIdx.x;
    const int lane = threadIdx.x;
    const float idv = x[(size_t)b * (CCH * TROW) + TT];   // x[b, 0, -1]
    const int sid = (int)(idv * 1e-6f + 0.5f) - 1;
    const float* W = fcw + (size_t)sid * (FEAT * NOUT);
    const float* base = pparts + (size_t)b * (NWB * NLOC * KOUT);
    float a0 = 0, a1 = 0, a2 = 0, a3 = 0;
    for (int f = lane; f < FEAT; f += 64) {
        int k = f / NWIN, win = f - k * NWIN;
        int u = (win < 5) ? win : (win + 3);
        float p = base[u * KOUT + k];
        float feat = fmaf(p * 0.01f, scale[k], shift[k]);
        a0 = fmaf(feat, W[f * 4 + 0], a0);
        a1 = fmaf(feat, W[f * 4 + 1], a1);
        a2 = fmaf(feat, W[f * 4 + 2], a2);
        a3 = fmaf(feat, W[f * 4 + 3], a3);
    }
#pragma unroll
    for (int m = 32; m; m >>= 1) {
        a0 += __shfl_xor(a0, m, 64);
        a1 += __shfl_xor(a1, m, 64);
        a2 += __shfl_xor(a2, m, 64);
        a3 += __shfl_xor(a3, m, 64);
    }
    if (lane == 0) {
        out[b * 4 + 0] = a0 + fcb[sid * 4 + 0];
        out[b * 4 + 1] = a1 + fcb[sid * 4 + 1];
        out[b * 4 + 2] = a2 + fcb[sid * 4 + 2];
        out[b * 4 + 3] = a3 + fcb[sid * 4 + 3];
    }
}

extern "C" void kernel_launch(void* const* d_in, const int* in_sizes, int n_in,
                              void* d_out, int out_size, void* d_ws, size_t ws_size,
                              hipStream_t stream) {
    const float* x     = (const float*)d_in[0];
    const float* cw    = (const float*)d_in[1];
    const float* cb    = (const float*)d_in[2];
    const float* gamma = (const float*)d_in[3];
    const float* beta  = (const float*)d_in[4];
    const float* fcw   = (const float*)d_in[5];
    const float* fcb   = (const float*)d_in[6];
    float* out = (float*)d_out;

    // workspace layout (no memset needed: every slot is plain-stored):
    //   pparts: NBLK*NLOC*KOUT f32 (pool-window partials)    9.17 MB
    //   spS/spQ: KOUT*NBLK f32 each (BN partials, transposed) 2.62 MB
    //   scale/shift: KOUT f32 each; wp: FKK*KP*32 bf16        58.4 KB
    float* pparts = (float*)d_ws;
    float* spS    = pparts + (size_t)NBLK * NLOC * KOUT;
    float* spQ    = spS + (size_t)KOUT * NBLK;
    float* scale  = spQ + (size_t)KOUT * NBLK;
    float* shift  = scale + KOUT;
    unsigned short* wpck = (unsigned short*)(shift + KOUT);

    pack_w_kernel<<<(FKK * KP * 32 + 255) / 256, 256, 0, stream>>>(cw, wpck);
    conv_mfma_kernel<<<dim3(NWB, BATCH), 256, 0, stream>>>(x, wpck, cb, pparts, spS, spQ);
    bn_stats_kernel<<<KOUT, 256, 0, stream>>>(spS, spQ, gamma, beta, scale, shift);
    fc_kernel<<<BATCH, 64, 0, stream>>>(x, pparts, scale, shift, fcw, fcb, out);
}

// Round 9
// 307.138 us; speedup vs baseline: 1.0773x; 1.0773x over previous
//
#include <hip/hip_runtime.h>

// Problem constants
#define BATCH 4096
#define CCH   22
#define TT    1001   // usable time samples (row length 1002; last elem = subject id)
#define TROW  1002
#define KOUT  40
#define KSZ   25
#define WOUT  977    // 1001 - 25 + 1
#define POOLW 100
#define NWIN  9
#define FEAT  360
#define NOUT  4

// Conv-MFMA tiling: 2 blocks along w, 512 computed w each, exclusive ownership
//   block 0: computes [0,512),   owns [0,500)    -> pool wins 0..4  (win0=0)
//   block 1: computes [488,1000) owns [500,977)  -> pool wins 5..8 + pseudo (win0=4)
// Every pool window has exactly ONE owning block (split at w=500, a POOLW edge).
#define WBLK  512
#define NWB   2
#define NBLK  (BATCH * NWB)    // 8192
//
// im2col-by-stride: LDS x-tile is [t][c] bf16 with row stride EXACTLY CSTG=24
// elements (48 B). Flattened reduction index f = j*24 + c is LINEAR in LDS
// (byte = w*48 + 2*f), so MFMA A-fragments are contiguous b128 reads crossing
// tap boundaries. K-steps: ceil(25*24/32) = 19. Pads (c in {22,23}, f >= 600)
// are neutralized by zeroed WEIGHTS; A may read arbitrary finite staged data.
#define CSTG  24               // padded channels (row = 48 B, 16B-aligned b128)
#define ROWB  48               // LDS row stride bytes
#define TSTG  544              // rows staged (need 537 = 512 + 25); 17 groups of 32
#define FKK   19               // MFMA K-steps of 32 over flattened (j,c)
#define KP    48               // k_out padded to 3 MFMA n-tiles
#define NLOC  7                // pool-window slots per block (wins win0..win0+6)
#define NMT   8                // m-tiles per wave (wave covers 128 w)

typedef __attribute__((ext_vector_type(8))) short short8;
typedef __attribute__((ext_vector_type(4))) float floatx4;

__device__ __forceinline__ unsigned short f2bf(float f) {
    unsigned u = __float_as_uint(f);
    u += 0x7fff + ((u >> 16) & 1);          // round-to-nearest-even
    return (unsigned short)(u >> 16);
}
// HW packed f32->bf16 RNE convert (same rounding as f2bf, 1 instr for 2 vals)
__device__ __forceinline__ unsigned cvt_pk_bf16(float a, float b) {
    unsigned r;
    asm("v_cvt_pk_bf16_f32 %0, %1, %2" : "=v"(r) : "v"(a), "v"(b));
    return r;
}
__device__ __forceinline__ float eluf(float v) {
    return v > 0.0f ? v : __expf(v) - 1.0f;
}

// Pack conv weights into MFMA B-operand layout over the flattened reduction:
// wp[kk][n=0..47][e=0..31] bf16, where f = kk*32+e, j = f/24, c = f%24.
__global__ __launch_bounds__(256) void pack_w_kernel(const float* __restrict__ cw,
                                                     unsigned short* __restrict__ wp) {
    int i = blockIdx.x * 256 + threadIdx.x;      // over FKK*KP*32 = 29184
    if (i >= FKK * KP * 32) return;
    int e = i & 31;
    int n = (i >> 5) % KP;
    int kk = i / (KP * 32);
    int f = kk * 32 + e;
    int j = f / CSTG, c = f - j * CSTG;
    float v = (n < KOUT && c < CCH && j < KSZ) ? cw[(n * CCH + c) * KSZ + j] : 0.0f;
    wp[i] = f2bf(v);
}

// Conv(bf16 MFMA) + bias + ELU + owned pool-window sums + owned BN partials.
// grid (NWB, BATCH), block 256 = 4 waves; wave wv owns 128 w's (8 m-tiles).
__global__ __launch_bounds__(256, 3) void conv_mfma_kernel(
        const float* __restrict__ x, const unsigned short* __restrict__ wp,
        const float* __restrict__ cb, float* __restrict__ pparts,
        float* __restrict__ spS, float* __restrict__ spQ) {
    __shared__ unsigned short xt[TSTG * CSTG];         // 544*48 B = 26112 B
    __shared__ float ps_s[NLOC * KP];                  // 1344 B
    __shared__ float st_q[KP];                         // 192 B

    const int bx = blockIdx.x, b = blockIdx.y;
    const int w0     = bx ? 488 : 0;     // first computed w
    const int ostart = bx ? 500 : 0;     // ownership [ostart, oend)
    const int oend   = bx ? WOUT : 500;
    const int win0   = bx ? 4 : 0;       // slot s holds pool window win0+s
    const int tid = threadIdx.x;
    const int wv = __builtin_amdgcn_readfirstlane(tid >> 6);
    const int lane = tid & 63;
    const size_t xb = (size_t)b * (CCH * TROW);

    for (int i = tid; i < NLOC * KP + KP; i += 256) {
        if (i < NLOC * KP) ps_s[i] = 0.0f;
        else st_q[i - NLOC * KP] = 0.0f;
    }

    // ---- stage x -> xt[t][c] bf16, row stride 48 B ----
    // 17 groups of 32 rows; lane = (row-in-group r5, c-half h of 12 channels)
    {
        const int r5 = lane & 31, h = lane >> 5;
#pragma unroll
        for (int it = 0; it < 5; ++it) {
            int idx = it * 4 + wv;                   // 0..19, active 0..16
            if (idx < 17) {
                int t_loc = idx * 32 + r5;
                int t_gl = w0 + t_loc;
                float v[12];
#pragma unroll
                for (int r = 0; r < 12; ++r) {
                    int c = h * 12 + r;
                    v[r] = (c < CCH && t_gl < TT) ? x[xb + (size_t)c * TROW + t_gl] : 0.0f;
                }
                unsigned u[6];
#pragma unroll
                for (int r = 0; r < 6; ++r) u[r] = cvt_pk_bf16(v[2 * r], v[2 * r + 1]);
                char* dst = (char*)xt + t_loc * ROWB + h * 24;
                *(uint2*)(dst)      = make_uint2(u[0], u[1]);
                *(uint2*)(dst + 8)  = make_uint2(u[2], u[3]);
                *(uint2*)(dst + 16) = make_uint2(u[4], u[5]);
            }
        }
    }
    __syncthreads();

    // ---- MFMA kk-loop: 19 K-steps of 32 over flattened (j,c), acc preloaded w/ bias ----
    const int m16 = lane & 15, g = lane >> 4;
    floatx4 acc[NMT][3];
#pragma unroll
    for (int nt = 0; nt < 3; ++nt) {
        int k = nt * 16 + m16;
        float bv = (k < KOUT) ? cb[k] : 0.0f;
#pragma unroll
        for (int mt = 0; mt < NMT; ++mt) acc[mt][nt] = (floatx4){bv, bv, bv, bv};
    }
    const char* ap = (const char*)xt + (wv * 128 + m16) * ROWB + g * 16;
    const unsigned short* wpl = wp + m16 * 32 + g * 8;

    short8 bfr[3];
#pragma unroll
    for (int nt = 0; nt < 3; ++nt)
        bfr[nt] = *(const short8*)(wpl + nt * 16 * 32);

#pragma unroll 1
    for (int kk = 0; kk < FKK; ++kk) {
        short8 bnx[3];
        if (kk + 1 < FKK) {
            const unsigned short* wn = wpl + (kk + 1) * (KP * 32);
#pragma unroll
            for (int nt = 0; nt < 3; ++nt) bnx[nt] = *(const short8*)(wn + nt * 16 * 32);
        }
        // A-frags in two groups of 4 (keeps live regs ~16, 12-MFMA train each)
#pragma unroll
        for (int half = 0; half < 2; ++half) {
            short8 afr[4];
#pragma unroll
            for (int q = 0; q < 4; ++q)
                afr[q] = *(const short8*)(ap + (half * 4 + q) * (16 * ROWB));
#pragma unroll
            for (int q = 0; q < 4; ++q)
#pragma unroll
                for (int nt = 0; nt < 3; ++nt)
                    acc[half * 4 + q][nt] = __builtin_amdgcn_mfma_f32_16x16x32_bf16(
                        afr[q], bfr[nt], acc[half * 4 + q][nt], 0, 0, 0);
        }
        ap += 64;                                   // next 32 flattened elems
#pragma unroll
        for (int nt = 0; nt < 3; ++nt) bfr[nt] = bnx[nt];
    }

    // ---- epilogue: ELU, ownership mask, pool segmented-reduce, BN sumsq ----
    float qv[3] = {0.f, 0.f, 0.f};
#pragma unroll
    for (int mt = 0; mt < NMT; ++mt) {
        const int wbase = w0 + wv * 128 + mt * 16 + g * 4;  // 4-aligned quad
        const int win = wbase / POOLW;                      // quad never straddles
#pragma unroll
        for (int nt = 0; nt < 3; ++nt) {
            const int k = nt * 16 + m16;
            const bool kok = (k < KOUT);
            float psum = 0.f;
#pragma unroll
            for (int r = 0; r < 4; ++r) {
                int w = wbase + r;
                float e = eluf(acc[mt][nt][r]);
                e = (kok && w >= ostart && w < oend) ? e : 0.0f;  // exclusive ownership
                psum += e;
                qv[nt] = fmaf(e, e, qv[nt]);
            }
            // segmented reduce over the 4 row-groups (g), segments g-contiguous
            float o1 = __shfl_down(psum, 16); int w1 = __shfl_down(win, 16);
            if (lane < 48 && w1 == win) psum += o1;
            float o2 = __shfl_down(psum, 32); int w2 = __shfl_down(win, 32);
            if (lane < 32 && w2 == win) psum += o2;
            int wu = __shfl_up(win, 16);
            if (g == 0 || wu != win)
                atomicAdd(&ps_s[(win - win0) * KP + k], psum);
        }
    }
#pragma unroll
    for (int nt = 0; nt < 3; ++nt) {
        float q = qv[nt];
        q += __shfl_xor(q, 16);
        q += __shfl_xor(q, 32);
        if (g == 0) atomicAdd(&st_q[nt * 16 + m16], q);
    }
    __syncthreads();

    const int blk = b * NWB + bx;
    if (tid < KOUT) {
        // stats sum = sum of all owned pool slots (incl. pseudo/zero windows)
        float s = 0.0f;
#pragma unroll
        for (int wl = 0; wl < NLOC; ++wl) s += ps_s[wl * KP + tid];
        spS[(size_t)tid * NBLK + blk] = s;               // transposed: coalesced reduce
        spQ[(size_t)tid * NBLK + blk] = st_q[tid];
    }
    for (int i = tid; i < NLOC * KOUT; i += 256) {
        int wl = i / KOUT, k = i - wl * KOUT;
        pparts[((size_t)blk * NLOC + wl) * KOUT + k] = ps_s[wl * KP + k];
    }
}

// Reduce per-block stat partials -> BN scale/shift per k. grid KOUT.
__global__ __launch_bounds__(256) void bn_stats_kernel(
        const float* __restrict__ spS, const float* __restrict__ spQ,
        const float* __restrict__ gamma, const float* __restrict__ beta,
        float* __restrict__ scale, float* __restrict__ shift) {
    const int k = blockIdx.x;
    float s = 0.0f, q = 0.0f;
    for (int r = threadIdx.x; r < NBLK; r += 256) {
        s += spS[(size_t)k * NBLK + r];
        q += spQ[(size_t)k * NBLK + r];
    }
#pragma unroll
    for (int m = 32; m; m >>= 1) {
        s += __shfl_xor(s, m, 64);
        q += __shfl_xor(q, m, 64);
    }
    __shared__ float rs[4], rq[4];
    const int wid = threadIdx.x >> 6, lane = threadIdx.x & 63;
    if (lane == 0) { rs[wid] = s; rq[wid] = q; }
    __syncthreads();
    if (threadIdx.x == 0) {
        s = rs[0] + rs[1] + rs[2] + rs[3];
        q = rq[0] + rq[1] + rq[2] + rq[3];
        const float N = (float)BATCH * (float)WOUT;
        float mean = s / N;
        float var = q / N - mean * mean;
        float sc = gamma[k] / sqrtf(var + 1e-5f);
        scale[k] = sc;
        shift[k] = beta[k] - mean * sc;
    }
}

// Subject decode + BN-affine fold + 360x4 matvec.
// Each pool window has exactly one source slot:
//   win 0..4 -> block 0 slot win        (unit index win)
//   win 5..8 -> block 1 slot win-4      (unit index NLOC + win-4 = win+3)
__global__ __launch_bounds__(64) void fc_kernel(
        const float* __restrict__ x, const float* __restrict__ pparts,
        const float* __restrict__ scale, const float* __restrict__ shift,
        const float* __restrict__ fcw, const float* __restrict__ fcb,
        float* __restrict__ out) {
    const int b = blockIdx.x;
    const int lane = threadIdx.x;
    const float idv = x[(size_t)b * (CCH * TROW) + TT];   // x[b, 0, -1]
    const int sid = (int)(idv * 1e-6f + 0.5f) - 1;
    const float* W = fcw + (size_t)sid * (FEAT * NOUT);
    const float* base = pparts + (size_t)b * (NWB * NLOC * KOUT);
    float a0 = 0, a1 = 0, a2 = 0, a3 = 0;
    for (int f = lane; f < FEAT; f += 64) {
        int k = f / NWIN, win = f - k * NWIN;
        int u = (win < 5) ? win : (win + 3);
        float p = base[u * KOUT + k];
        float feat = fmaf(p * 0.01f, scale[k], shift[k]);
        a0 = fmaf(feat, W[f * 4 + 0], a0);
        a1 = fmaf(feat, W[f * 4 + 1], a1);
        a2 = fmaf(feat, W[f * 4 + 2], a2);
        a3 = fmaf(feat, W[f * 4 + 3], a3);
    }
#pragma unroll
    for (int m = 32; m; m >>= 1) {
        a0 += __shfl_xor(a0, m, 64);
        a1 += __shfl_xor(a1, m, 64);
        a2 += __shfl_xor(a2, m, 64);
        a3 += __shfl_xor(a3, m, 64);
    }
    if (lane == 0) {
        out[b * 4 + 0] = a0 + fcb[sid * 4 + 0];
        out[b * 4 + 1] = a1 + fcb[sid * 4 + 1];
        out[b * 4 + 2] = a2 + fcb[sid * 4 + 2];
        out[b * 4 + 3] = a3 + fcb[sid * 4 + 3];
    }
}

extern "C" void kernel_launch(void* const* d_in, const int* in_sizes, int n_in,
                              void* d_out, int out_size, void* d_ws, size_t ws_size,
                              hipStream_t stream) {
    const float* x     = (const float*)d_in[0];
    const float* cw    = (const float*)d_in[1];
    const float* cb    = (const float*)d_in[2];
    const float* gamma = (const float*)d_in[3];
    const float* beta  = (const float*)d_in[4];
    const float* fcw   = (const float*)d_in[5];
    const float* fcb   = (const float*)d_in[6];
    float* out = (float*)d_out;

    // workspace layout (no memset needed: every slot is plain-stored):
    //   pparts: NBLK*NLOC*KOUT f32 (pool-window partials)    9.17 MB
    //   spS/spQ: KOUT*NBLK f32 each (BN partials, transposed) 2.62 MB
    //   scale/shift: KOUT f32 each; wp: FKK*KP*32 bf16        58.4 KB
    float* pparts = (float*)d_ws;
    float* spS    = pparts + (size_t)NBLK * NLOC * KOUT;
    float* spQ    = spS + (size_t)KOUT * NBLK;
    float* scale  = spQ + (size_t)KOUT * NBLK;
    float* shift  = scale + KOUT;
    unsigned short* wpck = (unsigned short*)(shift + KOUT);

    pack_w_kernel<<<(FKK * KP * 32 + 255) / 256, 256, 0, stream>>>(cw, wpck);
    conv_mfma_kernel<<<dim3(NWB, BATCH), 256, 0, stream>>>(x, wpck, cb, pparts, spS, spQ);
    bn_stats_kernel<<<KOUT, 256, 0, stream>>>(spS, spQ, gamma, beta, scale, shift);
    fc_kernel<<<BATCH, 64, 0, stream>>>(x, pparts, scale, shift, fcw, fcb, out);
}

// Round 10
// 307.056 us; speedup vs baseline: 1.0776x; 1.0003x over previous
//
#include <hip/hip_runtime.h>

// Problem constants
#define BATCH 4096
#define CCH   22
#define TT    1001   // usable time samples (row length 1002; last elem = subject id)
#define TROW  1002
#define KOUT  40
#define KSZ   25
#define WOUT  977    // 1001 - 25 + 1
#define POOLW 100
#define NWIN  9
#define FEAT  360
#define NOUT  4

// Conv-MFMA tiling: 2 blocks along w, 512 computed w each, exclusive ownership
//   block 0: computes [0,512),   owns [0,500)    -> pool wins 0..4  (win0=0)
//   block 1: computes [488,1000) owns [500,977)  -> pool wins 5..8 + pseudo (win0=4)
// Every pool window has exactly ONE owning block (split at w=500, a POOLW edge).
#define WBLK  512
#define NWB   2
#define NBLK  (BATCH * NWB)    // 8192
//
// im2col-by-stride: LDS x-tile is [t][c] bf16 with row stride EXACTLY CSTG=24
// elements (48 B). Flattened reduction index f = j*24 + c is LINEAR in LDS
// (byte = w*48 + 2*f), so MFMA A-fragments are contiguous b128 reads crossing
// tap boundaries. K-steps: ceil(25*24/32) = 19. Pads (c in {22,23}, f >= 600)
// are neutralized by zeroed WEIGHTS; A may read arbitrary finite staged data.
#define CSTG  24               // padded channels (row = 48 B, 16B-aligned b128)
#define ROWB  48               // LDS row stride bytes
#define TSTG  544              // rows staged (need 537 = 512 + 25); 17 groups of 32
#define FKK   19               // MFMA K-steps of 32 over flattened (j,c)
#define KP    48               // k_out padded to 3 MFMA n-tiles
#define NLOC  7                // pool-window slots per block (wins win0..win0+6)
#define NMT   8                // m-tiles per wave (wave covers 128 w)
#define NSU   (17 * 48)        // stage units: 17 groups x (8 t-quads x 6 c-quads)

typedef __attribute__((ext_vector_type(8))) short short8;
typedef __attribute__((ext_vector_type(4))) float floatx4;

__device__ __forceinline__ unsigned short f2bf(float f) {
    unsigned u = __float_as_uint(f);
    u += 0x7fff + ((u >> 16) & 1);          // round-to-nearest-even
    return (unsigned short)(u >> 16);
}
// HW packed f32->bf16 RNE convert (same rounding as f2bf, 1 instr for 2 vals)
__device__ __forceinline__ unsigned cvt_pk_bf16(float a, float b) {
    unsigned r;
    asm("v_cvt_pk_bf16_f32 %0, %1, %2" : "=v"(r) : "v"(a), "v"(b));
    return r;
}
__device__ __forceinline__ float eluf(float v) {
    return v > 0.0f ? v : __expf(v) - 1.0f;
}

// Pack conv weights into MFMA B-operand layout over the flattened reduction:
// wp[kk][n=0..47][e=0..31] bf16, where f = kk*32+e, j = f/24, c = f%24.
__global__ __launch_bounds__(256) void pack_w_kernel(const float* __restrict__ cw,
                                                     unsigned short* __restrict__ wp) {
    int i = blockIdx.x * 256 + threadIdx.x;      // over FKK*KP*32 = 29184
    if (i >= FKK * KP * 32) return;
    int e = i & 31;
    int n = (i >> 5) % KP;
    int kk = i / (KP * 32);
    int f = kk * 32 + e;
    int j = f / CSTG, c = f - j * CSTG;
    float v = (n < KOUT && c < CCH && j < KSZ) ? cw[(n * CCH + c) * KSZ + j] : 0.0f;
    wp[i] = f2bf(v);
}

// Conv(bf16 MFMA) + bias + ELU + owned pool-window sums + owned BN partials.
// grid (NWB, BATCH), block 256 = 4 waves; wave wv owns 128 w's (8 m-tiles).
__global__ __launch_bounds__(256, 3) void conv_mfma_kernel(
        const float* __restrict__ x, const unsigned short* __restrict__ wp,
        const float* __restrict__ cb, float* __restrict__ pparts,
        float* __restrict__ spS, float* __restrict__ spQ) {
    __shared__ unsigned short xt[TSTG * CSTG];         // 544*48 B = 26112 B
    __shared__ float ps_s[NLOC * KP];                  // 1344 B
    __shared__ float st_q[KP];                         // 192 B

    const int bx = blockIdx.x, b = blockIdx.y;
    const int w0     = bx ? 488 : 0;     // first computed w
    const int ostart = bx ? 500 : 0;     // ownership [ostart, oend)
    const int oend   = bx ? WOUT : 500;
    const int win0   = bx ? 4 : 0;       // slot s holds pool window win0+s
    const int tid = threadIdx.x;
    const int wv = __builtin_amdgcn_readfirstlane(tid >> 6);
    const int lane = tid & 63;
    const size_t xb = (size_t)b * (CCH * TROW);

    for (int i = tid; i < NLOC * KP + KP; i += 256) {
        if (i < NLOC * KP) ps_s[i] = 0.0f;
        else st_q[i - NLOC * KP] = 0.0f;
    }

    // ---- stage x -> xt[t][c] bf16, row stride 48 B, float2-vectorized ----
    // Unit u: grp = u/48 (32-row group), r = u%48: tq = r&7 (t-quad),
    // cq = r>>3 (4-channel quad). Lane loads x[c][t..t+3] as 2x float2 per
    // channel (8B loads are alignment-safe for ALL c: 1002*4 % 8 == 0 and
    // t_gl % 4 == 0), transposes 4x4 in-register, writes 4 x ds_write_b64.
    // Per-thread global loads: ~20 vec vs 51 scalar in the unvectorized form.
    {
#pragma unroll
        for (int it = 0; it < 4; ++it) {
            int u = it * 256 + tid;
            if (u < NSU) {
                int grp = u / 48, r = u - grp * 48;
                int tq = r & 7, cq = r >> 3;
                int t_loc = grp * 32 + tq * 4;
                int t_gl = w0 + t_loc;
                int c0 = cq * 4;
                float f[4][4];                       // [ci][ti]
                if (t_gl + 3 < TT) {                 // full quad of real t (<=1000)
#pragma unroll
                    for (int ci = 0; ci < 4; ++ci) {
                        int c = c0 + ci;
                        if (c < CCH) {
                            const float* p = x + xb + (size_t)c * TROW + t_gl;
                            float2 v0 = *(const float2*)(p);
                            float2 v1 = *(const float2*)(p + 2);
                            f[ci][0] = v0.x; f[ci][1] = v0.y;
                            f[ci][2] = v1.x; f[ci][3] = v1.y;
                        } else {
                            f[ci][0] = 0.f; f[ci][1] = 0.f;
                            f[ci][2] = 0.f; f[ci][3] = 0.f;
                        }
                    }
                } else {                              // boundary: guarded scalars
#pragma unroll
                    for (int ci = 0; ci < 4; ++ci) {
                        int c = c0 + ci;
#pragma unroll
                        for (int ti = 0; ti < 4; ++ti) {
                            int t = t_gl + ti;
                            f[ci][ti] = (c < CCH && t < TT)
                                            ? x[xb + (size_t)c * TROW + t] : 0.f;
                        }
                    }
                }
#pragma unroll
                for (int ti = 0; ti < 4; ++ti) {
                    unsigned lo = cvt_pk_bf16(f[0][ti], f[1][ti]);
                    unsigned hi = cvt_pk_bf16(f[2][ti], f[3][ti]);
                    *(uint2*)((char*)xt + (t_loc + ti) * ROWB + cq * 8)
                        = make_uint2(lo, hi);
                }
            }
        }
    }
    __syncthreads();

    // ---- MFMA kk-loop: 19 K-steps of 32 over flattened (j,c), acc preloaded w/ bias ----
    const int m16 = lane & 15, g = lane >> 4;
    floatx4 acc[NMT][3];
#pragma unroll
    for (int nt = 0; nt < 3; ++nt) {
        int k = nt * 16 + m16;
        float bv = (k < KOUT) ? cb[k] : 0.0f;
#pragma unroll
        for (int mt = 0; mt < NMT; ++mt) acc[mt][nt] = (floatx4){bv, bv, bv, bv};
    }
    const char* ap = (const char*)xt + (wv * 128 + m16) * ROWB + g * 16;
    const unsigned short* wpl = wp + m16 * 32 + g * 8;

    short8 bfr[3];
#pragma unroll
    for (int nt = 0; nt < 3; ++nt)
        bfr[nt] = *(const short8*)(wpl + nt * 16 * 32);

#pragma unroll 1
    for (int kk = 0; kk < FKK; ++kk) {
        short8 bnx[3];
        if (kk + 1 < FKK) {
            const unsigned short* wn = wpl + (kk + 1) * (KP * 32);
#pragma unroll
            for (int nt = 0; nt < 3; ++nt) bnx[nt] = *(const short8*)(wn + nt * 16 * 32);
        }
        // A-frags in two groups of 4 (keeps live regs ~16, 12-MFMA train each)
#pragma unroll
        for (int half = 0; half < 2; ++half) {
            short8 afr[4];
#pragma unroll
            for (int q = 0; q < 4; ++q)
                afr[q] = *(const short8*)(ap + (half * 4 + q) * (16 * ROWB));
#pragma unroll
            for (int q = 0; q < 4; ++q)
#pragma unroll
                for (int nt = 0; nt < 3; ++nt)
                    acc[half * 4 + q][nt] = __builtin_amdgcn_mfma_f32_16x16x32_bf16(
                        afr[q], bfr[nt], acc[half * 4 + q][nt], 0, 0, 0);
        }
        ap += 64;                                   // next 32 flattened elems
#pragma unroll
        for (int nt = 0; nt < 3; ++nt) bfr[nt] = bnx[nt];
    }

    // ---- epilogue: ELU, ownership mask, pool segmented-reduce, BN sumsq ----
    float qv[3] = {0.f, 0.f, 0.f};
#pragma unroll
    for (int mt = 0; mt < NMT; ++mt) {
        const int wbase = w0 + wv * 128 + mt * 16 + g * 4;  // 4-aligned quad
        const int win = wbase / POOLW;                      // quad never straddles
#pragma unroll
        for (int nt = 0; nt < 3; ++nt) {
            const int k = nt * 16 + m16;
            const bool kok = (k < KOUT);
            float psum = 0.f;
#pragma unroll
            for (int r = 0; r < 4; ++r) {
                int w = wbase + r;
                float e = eluf(acc[mt][nt][r]);
                e = (kok && w >= ostart && w < oend) ? e : 0.0f;  // exclusive ownership
                psum += e;
                qv[nt] = fmaf(e, e, qv[nt]);
            }
            // segmented reduce over the 4 row-groups (g), segments g-contiguous
            float o1 = __shfl_down(psum, 16); int w1 = __shfl_down(win, 16);
            if (lane < 48 && w1 == win) psum += o1;
            float o2 = __shfl_down(psum, 32); int w2 = __shfl_down(win, 32);
            if (lane < 32 && w2 == win) psum += o2;
            int wu = __shfl_up(win, 16);
            if (g == 0 || wu != win)
                atomicAdd(&ps_s[(win - win0) * KP + k], psum);
        }
    }
#pragma unroll
    for (int nt = 0; nt < 3; ++nt) {
        float q = qv[nt];
        q += __shfl_xor(q, 16);
        q += __shfl_xor(q, 32);
        if (g == 0) atomicAdd(&st_q[nt * 16 + m16], q);
    }
    __syncthreads();

    const int blk = b * NWB + bx;
    if (tid < KOUT) {
        // stats sum = sum of all owned pool slots (incl. pseudo/zero windows)
        float s = 0.0f;
#pragma unroll
        for (int wl = 0; wl < NLOC; ++wl) s += ps_s[wl * KP + tid];
        spS[(size_t)tid * NBLK + blk] = s;               // transposed: coalesced reduce
        spQ[(size_t)tid * NBLK + blk] = st_q[tid];
    }
    for (int i = tid; i < NLOC * KOUT; i += 256) {
        int wl = i / KOUT, k = i - wl * KOUT;
        pparts[((size_t)blk * NLOC + wl) * KOUT + k] = ps_s[wl * KP + k];
    }
}

// Reduce per-block stat partials -> BN scale/shift per k. grid KOUT.
__global__ __launch_bounds__(256) void bn_stats_kernel(
        const float* __restrict__ spS, const float* __restrict__ spQ,
        const float* __restrict__ gamma, const float* __restrict__ beta,
        float* __restrict__ scale, float* __restrict__ shift) {
    const int k = blockIdx.x;
    float s = 0.0f, q = 0.0f;
    for (int r = threadIdx.x; r < NBLK; r += 256) {
        s += spS[(size_t)k * NBLK + r];
        q += spQ[(size_t)k * NBLK + r];
    }
#pragma unroll
    for (int m = 32; m; m >>= 1) {
        s += __shfl_xor(s, m, 64);
        q += __shfl_xor(q, m, 64);
    }
    __shared__ float rs[4], rq[4];
    const int wid = threadIdx.x >> 6, lane = threadIdx.x & 63;
    if (lane == 0) { rs[wid] = s; rq[wid] = q; }
    __syncthreads();
    if (threadIdx.x == 0) {
        s = rs[0] + rs[1] + rs[2] + rs[3];
        q = rq[0] + rq[1] + rq[2] + rq[3];
        const float N = (float)BATCH * (float)WOUT;
        float mean = s / N;
        float var = q / N - mean * mean;
        float sc = gamma[k] / sqrtf(var + 1e-5f);
        scale[k] = sc;
        shift[k] = beta[k] - mean * sc;
    }
}

// Subject decode + BN-affine fold + 360x4 matvec.
// Each pool window has exactly one source slot:
//   win 0..4 -> block 0 slot win        (unit index win)
//   win 5..8 -> block 1 slot win-4      (unit index NLOC + win-4 = win+3)
__global__ __launch_bounds__(64) void fc_kernel(
        const float* __restrict__ x, const float* __restrict__ pparts,
        const float* __restrict__ scale, const float* __restrict__ shift,
        const float* __restrict__ fcw, const float* __restrict__ fcb,
        float* __restrict__ out) {
    const int b = blockIdx.x;
    const int lane = threadIdx.x;
    const float idv = x[(size_t)b * (CCH * TROW) + TT];   // x[b, 0, -1]
    const int sid = (int)(idv * 1e-6f + 0.5f) - 1;
    const float* W = fcw + (size_t)sid * (FEAT * NOUT);
    const float* base = pparts + (size_t)b * (NWB * NLOC * KOUT);
    float a0 = 0, a1 = 0, a2 = 0, a3 = 0;
    for (int f = lane; f < FEAT; f += 64) {
        int k = f / NWIN, win = f - k * NWIN;
        int u = (win < 5) ? win : (win + 3);
        float p = base[u * KOUT + k];
        float feat = fmaf(p * 0.01f, scale[k], shift[k]);
        a0 = fmaf(feat, W[f * 4 + 0], a0);
        a1 = fmaf(feat, W[f * 4 + 1], a1);
        a2 = fmaf(feat, W[f * 4 + 2], a2);
        a3 = fmaf(feat, W[f * 4 + 3], a3);
    }
#pragma unroll
    for (int m = 32; m; m >>= 1) {
        a0 += __shfl_xor(a0, m, 64);
        a1 += __shfl_xor(a1, m, 64);
        a2 += __shfl_xor(a2, m, 64);
        a3 += __shfl_xor(a3, m, 64);
    }
    if (lane == 0) {
        out[b * 4 + 0] = a0 + fcb[sid * 4 + 0];
        out[b * 4 + 1] = a1 + fcb[sid * 4 + 1];
        out[b * 4 + 2] = a2 + fcb[sid * 4 + 2];
        out[b * 4 + 3] = a3 + fcb[sid * 4 + 3];
    }
}

extern "C" void kernel_launch(void* const* d_in, const int* in_sizes, int n_in,
                              void* d_out, int out_size, void* d_ws, size_t ws_size,
                              hipStream_t stream) {
    const float* x     = (const float*)d_in[0];
    const float* cw    = (const float*)d_in[1];
    const float* cb    = (const float*)d_in[2];
    const float* gamma = (const float*)d_in[3];
    const float* beta  = (const float*)d_in[4];
    const float* fcw   = (const float*)d_in[5];
    const float* fcb   = (const float*)d_in[6];
    float* out = (float*)d_out;

    // workspace layout (no memset needed: every slot is plain-stored):
    //   pparts: NBLK*NLOC*KOUT f32 (pool-window partials)    9.17 MB
    //   spS/spQ: KOUT*NBLK f32 each (BN partials, transposed) 2.62 MB
    //   scale/shift: KOUT f32 each; wp: FKK*KP*32 bf16        58.4 KB
    float* pparts = (float*)d_ws;
    float* spS    = pparts + (size_t)NBLK * NLOC * KOUT;
    float* spQ    = spS + (size_t)KOUT * NBLK;
    float* scale  = spQ + (size_t)KOUT * NBLK;
    float* shift  = scale + KOUT;
    unsigned short* wpck = (unsigned short*)(shift + KOUT);

    pack_w_kernel<<<(FKK * KP * 32 + 255) / 256, 256, 0, stream>>>(cw, wpck);
    conv_mfma_kernel<<<dim3(NWB, BATCH), 256, 0, stream>>>(x, wpck, cb, pparts, spS, spQ);
    bn_stats_kernel<<<KOUT, 256, 0, stream>>>(spS, spQ, gamma, beta, scale, shift);
    fc_kernel<<<BATCH, 64, 0, stream>>>(x, pparts, scale, shift, fcw, fcb, out);
}